// Round 11
// baseline (11379.310 us; speedup 1.0000x reference)
//
#include <hip/hip_runtime.h>

#define B_   16
#define T_   1600
#define D_   512
#define U_   1024
#define G_   4096
#define NWG  64             // 32 per direction, 32 units per WG
#define TPB  1024           // 16 waves: 8 col-tiles x 2 khalf
#define NCOL 128            // 32 units x 4 gates (col = gate*32 + unit)
#define GSTR 132            // gates row stride (floats)
#define SSTR 392            // weight staging row stride (ushorts): 384 + 8
#define XBOFF 16896         // gates bytes = 2*16*132*4
#define HOFF  33280         // XBOFF + 16384 (x image)
#define SMEM_BYTES 100352   // staging 128*392*2 dominates (runtime uses 66,048)
#define X16OFF (1 << 18)    // 4 x 64KB tagged h images fill [0, 256KB)

typedef __attribute__((ext_vector_type(8))) __bf16 bf16x8;
typedef __attribute__((ext_vector_type(4))) float  f32x4;
typedef __attribute__((ext_vector_type(2))) float  f32x2;
typedef __attribute__((ext_vector_type(4))) unsigned int uint4v;
typedef __attribute__((ext_vector_type(8))) unsigned short us8v;
typedef unsigned long long u64;
typedef unsigned int u32;

__device__ __forceinline__ unsigned short f2bf(float f) {
  unsigned u = __builtin_bit_cast(unsigned, f);
  u += 0x7FFFu + ((u >> 16) & 1u);          // RNE
  return (unsigned short)(u >> 16);
}
__device__ __forceinline__ bf16x8 cvt8(const float4 a, const float4 b) {
  us8v r;
  r[0]=f2bf(a.x); r[1]=f2bf(a.y); r[2]=f2bf(a.z); r[3]=f2bf(a.w);
  r[4]=f2bf(b.x); r[5]=f2bf(b.y); r[6]=f2bf(b.z); r[7]=f2bf(b.w);
  return __builtin_bit_cast(bf16x8, r);
}
__device__ __forceinline__ float sigm(float x){ return 1.f / (1.f + __expf(-x)); }
__device__ __forceinline__ float tanh_(float x){ return 1.f - 2.f / (__expf(2.f*x) + 1.f); }

// one-time x fp32 -> bf16
extern "C" __global__ void __launch_bounds__(256)
xcvt_kernel(const float* __restrict__ xin, unsigned short* __restrict__ x16) {
  const size_t i = ((size_t)blockIdx.x*256 + threadIdx.x) * 8;
  float4 a = *(const float4*)(xin + i);
  float4 b = *(const float4*)(xin + i + 4);
  *(us8v*)(x16 + i) = __builtin_bit_cast(us8v, cvt8(a, b));
}

extern "C" __global__ void __launch_bounds__(TPB, 1)
bilstm_kernel(const float* __restrict__ x, const int* __restrict__ xlen,
              const float* __restrict__ kf, const float* __restrict__ rkf, const float* __restrict__ bf_,
              const float* __restrict__ kb, const float* __restrict__ rkb, const float* __restrict__ bb_,
              float* __restrict__ out, u32* __restrict__ hbuf32,
              const unsigned short* __restrict__ x16, int use16)
{
  extern __shared__ char smem[];

  const int tid  = threadIdx.x;
  const int wg   = blockIdx.x;
  const int dir  = wg >> 5;
  const int slot = wg & 31;
  const int u0   = slot << 5;         // 32 units per WG

  if (wg == 0 && tid < B_)
    out[(size_t)B_*T_*2*U_ + tid] = (float)xlen[tid];

  const float* Km = dir ? kb  : kf;
  const float* Rm = dir ? rkb : rkf;
  const float* Bv = dir ? bb_ : bf_;

  const int w = tid >> 6, l = tid & 63;
  const int ntile = w >> 1, khalf = w & 1;
  const int fr8 = (l >> 4) << 3;
  const int col = ntile*16 + (l & 15);

  // ---- one-time: 4-pass weight staging + frag extraction into VGPRs ----
  bf16x8 wx[8], wh[16];
  {
    unsigned short* stag = (unsigned short*)smem;
    #pragma unroll
    for (int p = 0; p < 4; ++p) {
      for (int i = tid; i < 384*NCOL; i += TPB) {
        int kl = i >> 7, c = i & 127;
        int k = p*384 + kl;
        int gc = (c >> 5)*1024 + u0 + (c & 31);     // gate*1024 + unit
        float wv = (k < D_) ? Km[(size_t)k*G_ + gc] : Rm[(size_t)(k-D_)*G_ + gc];
        stag[c*SSTR + kl] = f2bf(wv);
      }
      __syncthreads();
      const unsigned short* srow = stag + col*SSTR;
      #pragma unroll
      for (int i = 0; i < 8; ++i) {
        int kb_ = khalf*256 + i*32;                 // x frag k-base (<512)
        if (kb_/384 == p) wx[i] = *(const bf16x8*)(srow + (kb_ - p*384) + fr8);
      }
      #pragma unroll
      for (int i = 0; i < 16; ++i) {
        int kb_ = 512 + khalf*512 + i*32;           // h frag k-base
        if (kb_/384 == p) wh[i] = *(const bf16x8*)(srow + (kb_ - p*384) + fr8);
      }
      __syncthreads();
    }
  }

  float* gates = (float*)smem;          // [2 khalf][16 b][GSTR]
  char*  xbuf  = smem + XBOFF;          // [16 b][1024 B] swizzled bf16 x(t)
  char*  hst   = smem + HOFF;           // [16 b][2048 B] swizzled bf16 h(t-1)
  float* gp    = gates + khalf*(16*GSTR);
  const int drow0 = (l >> 4) << 2;

  // epilogue state (waves 0-3: 256 lanes): b = tid>>4, units eu, eu+1
  const int eb = tid >> 4, eu = (tid & 15) << 1;
  float bias[8]; float cc0 = 0.f, cc1 = 0.f;
  if (tid < 256) {
    #pragma unroll
    for (int g = 0; g < 4; ++g) {
      bias[g]     = Bv[g*1024 + u0 + eu];
      bias[4 + g] = Bv[g*1024 + u0 + eu + 1];
    }
  }

  // x staging lane map: wave w stages batch row w's 8 bf16 at (tid&63)*8
  const int sxb = tid >> 6, sxk = (tid & 63) << 3;
  const unsigned short* x16row = x16 + (size_t)sxb*T_*D_ + sxk;
  const float*          xf32row = x + (size_t)sxb*T_*D_ + sxk;
  char* xdst = xbuf + sxb*1024;
  const int xswz = (sxb & 7) << 4;

  // MFMA A-frag read bases
  const char* xrow = xbuf + (l & 15)*1024;
  const char* hrow = hst + (l & 15)*2048;
  const int   swz  = ((l & 15) & 7) << 4;

  // consumer poll map: thread covers 4 x 16B chunks of the 64KB tagged image
  const unsigned off0 = (unsigned)tid * 16;
  const int hb_b0 = tid >> 8;                 // + 4*j  -> batch row
  const int hb_u  = (tid & 255) << 2;         // unit base (4 units per chunk)

  // prologue: stage x(t=0)
  {
    const int tg0 = dir ? (T_ - 1) : 0;
    if (use16) {
      *(bf16x8*)(xdst + ((sxk << 1) ^ xswz)) = *(const bf16x8*)(x16row + (size_t)tg0*D_);
    } else {
      float4 a = *(const float4*)(xf32row + (size_t)tg0*D_);
      float4 b = *(const float4*)(xf32row + (size_t)tg0*D_ + 4);
      *(bf16x8*)(xdst + ((sxk << 1) ^ xswz)) = cvt8(a, b);
    }
  }

  for (int t = 0; t < T_; ++t) {
    const int tg = dir ? (T_ - 1 - t) : t;

    if (t > 0) {
      // fused poll+load: retry until all 8B granules carry tag t
      const u32* hb = hbuf32 + (size_t)((t & 1)*2 + dir) * 16384;
      const unsigned tagv = (unsigned)t << 16;
      uint4v hv[4];
      long long guard = 0;
      for (;;) {
        #pragma unroll
        for (int j = 0; j < 4; ++j)
          asm volatile("global_load_dwordx4 %0, %1, %2 sc0 sc1"
                       : "=v"(hv[j]) : "v"(off0 + (unsigned)(j*16384)), "s"(hb));
        asm volatile("s_waitcnt vmcnt(0)" ::: "memory");
        __builtin_amdgcn_sched_barrier(0);
        unsigned bad = 0;
        #pragma unroll
        for (int j = 0; j < 4; ++j)
          bad |= (hv[j][0] ^ tagv) | (hv[j][2] ^ tagv);
        if (!(bad & 0xFFFF0000u)) break;
        __builtin_amdgcn_s_sleep(1);
        if (++guard > (1LL << 22)) break;
      }
      // strip tags, stage to LDS (swizzled)
      #pragma unroll
      for (int j = 0; j < 4; ++j) {
        u32 lo = __builtin_amdgcn_perm(hv[j][1], hv[j][0], 0x05040100u);
        u32 hi = __builtin_amdgcn_perm(hv[j][3], hv[j][2], 0x05040100u);
        const int b = hb_b0 + 4*j;
        *(u64*)(hst + b*2048 + ((hb_u << 1) ^ ((b & 7) << 4))) = ((u64)hi << 32) | lo;
      }
    }
    __syncthreads();   // S2: h(t-1) + x(t) staged

    // MFMA: gates[b][128 cols] = [x(t) | h(t-1)] @ W  (khalf split)
    {
      f32x4 acc = {0.f,0.f,0.f,0.f}, acc2 = acc;
      #pragma unroll
      for (int i = 0; i < 8; i += 2) {
        bf16x8 a0 = *(const bf16x8*)(xrow + (((khalf*8 + i)*64     + (fr8 << 1)) ^ swz));
        bf16x8 a1 = *(const bf16x8*)(xrow + (((khalf*8 + i + 1)*64 + (fr8 << 1)) ^ swz));
        acc  = __builtin_amdgcn_mfma_f32_16x16x32_bf16(a0, wx[i],   acc,  0, 0, 0);
        acc2 = __builtin_amdgcn_mfma_f32_16x16x32_bf16(a1, wx[i+1], acc2, 0, 0, 0);
      }
      if (t > 0) {
        #pragma unroll
        for (int i = 0; i < 16; i += 2) {
          bf16x8 a0 = *(const bf16x8*)(hrow + ((khalf*1024 + i*64     + (fr8 << 1)) ^ swz));
          bf16x8 a1 = *(const bf16x8*)(hrow + ((khalf*1024 + (i+1)*64 + (fr8 << 1)) ^ swz));
          acc  = __builtin_amdgcn_mfma_f32_16x16x32_bf16(a0, wh[i],   acc,  0, 0, 0);
          acc2 = __builtin_amdgcn_mfma_f32_16x16x32_bf16(a1, wh[i+1], acc2, 0, 0, 0);
        }
      }
      acc += acc2;
      #pragma unroll
      for (int j = 0; j < 4; ++j) gp[(drow0 + j)*GSTR + col] = acc[j];
    }
    __syncthreads();   // S3: gates complete; xbuf reads done

    // epilogue: waves 0-3 (2 units per lane); tagged self-publishing h store
    if (tid < 256) {
      const float* ga = gates + eb*GSTR + eu;
      const float* gb2 = gates + (16 + eb)*GSTR + eu;
      f32x2 ia = *(const f32x2*)(ga);      f32x2 ib = *(const f32x2*)(gb2);
      f32x2 fa = *(const f32x2*)(ga + 32); f32x2 fb = *(const f32x2*)(gb2 + 32);
      f32x2 za = *(const f32x2*)(ga + 64); f32x2 zb = *(const f32x2*)(gb2 + 64);
      f32x2 oa = *(const f32x2*)(ga + 96); f32x2 ob = *(const f32x2*)(gb2 + 96);
      float gi0 = ia.x + ib.x + bias[0], gi1 = ia.y + ib.y + bias[4];
      float gf0 = fa.x + fb.x + bias[1], gf1 = fa.y + fb.y + bias[5];
      float gz0 = za.x + zb.x + bias[2], gz1 = za.y + zb.y + bias[6];
      float go0 = oa.x + ob.x + bias[3], go1 = oa.y + ob.y + bias[7];
      cc0 = sigm(gf0)*cc0 + sigm(gi0)*tanh_(gz0);
      cc1 = sigm(gf1)*cc1 + sigm(gi1)*tanh_(gz1);
      float h0 = sigm(go0)*tanh_(cc0);
      float h1 = sigm(go1)*tanh_(cc1);
      const unsigned tagw = (unsigned)(t + 1) << 16;
      u32 w0 = (u32)f2bf(h0) | tagw;
      u32 w1 = (u32)f2bf(h1) | tagw;
      u32* hdst = hbuf32 + (size_t)(((t & 1) ^ 1)*2 + dir)*16384 + (eb << 10) + u0 + eu;
      __hip_atomic_store((u64*)hdst, ((u64)w1 << 32) | w0, __ATOMIC_RELAXED, __HIP_MEMORY_SCOPE_AGENT);
      f32x2 ho; ho.x = h0; ho.y = h1;   // out store off the critical path, cached
      *(f32x2*)(out + ((size_t)eb*T_ + tg)*(2*U_) + (dir << 10) + u0 + eu) = ho;
    }

    if (t + 1 < T_) {
      // stage x(t+1) into LDS (plain cached loads; ordered by next S2)
      const int tg1 = dir ? (T_ - 2 - t) : (t + 1);
      if (use16) {
        *(bf16x8*)(xdst + ((sxk << 1) ^ xswz)) = *(const bf16x8*)(x16row + (size_t)tg1*D_);
      } else {
        float4 a = *(const float4*)(xf32row + (size_t)tg1*D_);
        float4 b = *(const float4*)(xf32row + (size_t)tg1*D_ + 4);
        *(bf16x8*)(xdst + ((sxk << 1) ^ xswz)) = cvt8(a, b);
      }
    }
  }
}

extern "C" void kernel_launch(void* const* d_in, const int* in_sizes, int n_in,
                              void* d_out, int out_size, void* d_ws, size_t ws_size,
                              hipStream_t stream) {
  const float* x   = (const float*)d_in[0];
  const int*   xl  = (const int*)d_in[1];
  const float* kf  = (const float*)d_in[2];
  const float* rkf = (const float*)d_in[3];
  const float* bf_ = (const float*)d_in[4];
  const float* kb  = (const float*)d_in[5];
  const float* rkb = (const float*)d_in[6];
  const float* bb_ = (const float*)d_in[7];
  float* out = (float*)d_out;

  u32* hbuf32 = (u32*)d_ws;                                       // 4 x 64KB tagged h images
  unsigned short* x16 = (unsigned short*)((char*)d_ws + X16OFF);  // 26.2 MB bf16 x

  const size_t need = (size_t)X16OFF + (size_t)B_*T_*D_*2;
  const int use16 = (ws_size >= need) ? 1 : 0;

  (void)hipMemsetAsync(d_ws, 0, X16OFF, stream);    // zero all tags (graph-safe)
  if (use16)
    xcvt_kernel<<<6400, 256, 0, stream>>>(x, x16);

  bilstm_kernel<<<NWG, TPB, SMEM_BYTES, stream>>>(x, xl, kf, rkf, bf_, kb, rkb, bb_,
                                                  out, hbuf32, x16, use16);
}

// Round 12
// 5521.445 us; speedup vs baseline: 2.0609x; 2.0609x over previous
//
#include <hip/hip_runtime.h>

#define B_   16
#define T_   1600
#define D_   512
#define U_   1024
#define G_   4096
#define NWG  128            // 64 per direction, 16 units per WG
#define TPB  512            // 8 waves: 4 col-tiles x 2 khalf
#define NCOL 64             // 16 units x 4 gates (col = gate*16 + unit)
#define GSTR 68             // gates row stride (floats); 68 % 32 = 4
#define SSTR 776            // weight staging row stride (ushorts): 768 + 8
#define HSTOFF 12288        // LDS: h payload image [16 b][2048 B], XOR-swizzled
#define SMEM_BYTES 99328    // staging [64][776] ushorts dominates (runtime: 45,056)
#define X16OFF (1 << 18)    // 4 x 64KB tagged h images fill [0, 256KB)

typedef __attribute__((ext_vector_type(8))) __bf16 bf16x8;
typedef __attribute__((ext_vector_type(4))) float  f32x4;
typedef __attribute__((ext_vector_type(2))) float  f32x2;
typedef __attribute__((ext_vector_type(4))) unsigned int uint4v;
typedef __attribute__((ext_vector_type(8))) unsigned short us8v;
typedef unsigned long long u64;
typedef unsigned int u32;

__device__ __forceinline__ unsigned short f2bf(float f) {
  unsigned u = __builtin_bit_cast(unsigned, f);
  u += 0x7FFFu + ((u >> 16) & 1u);          // RNE
  return (unsigned short)(u >> 16);
}
__device__ __forceinline__ bf16x8 cvt8(const float4 a, const float4 b) {
  us8v r;
  r[0]=f2bf(a.x); r[1]=f2bf(a.y); r[2]=f2bf(a.z); r[3]=f2bf(a.w);
  r[4]=f2bf(b.x); r[5]=f2bf(b.y); r[6]=f2bf(b.z); r[7]=f2bf(b.w);
  return __builtin_bit_cast(bf16x8, r);
}
__device__ __forceinline__ float sigm(float x){ return 1.f / (1.f + __expf(-x)); }
__device__ __forceinline__ float tanh_(float x){ return 1.f - 2.f / (__expf(2.f*x) + 1.f); }

// one-time x fp32 -> bf16
extern "C" __global__ void __launch_bounds__(256)
xcvt_kernel(const float* __restrict__ xin, unsigned short* __restrict__ x16) {
  const size_t i = ((size_t)blockIdx.x*256 + threadIdx.x) * 8;
  float4 a = *(const float4*)(xin + i);
  float4 b = *(const float4*)(xin + i + 4);
  *(us8v*)(x16 + i) = __builtin_bit_cast(us8v, cvt8(a, b));
}

extern "C" __global__ void __launch_bounds__(TPB, 1)
bilstm_kernel(const float* __restrict__ x, const int* __restrict__ xlen,
              const float* __restrict__ kf, const float* __restrict__ rkf, const float* __restrict__ bf_,
              const float* __restrict__ kb, const float* __restrict__ rkb, const float* __restrict__ bb_,
              float* __restrict__ out, u32* __restrict__ hbuf32,
              const unsigned short* __restrict__ x16, int use16)
{
  extern __shared__ char smem[];

  const int tid  = threadIdx.x;
  const int wg   = blockIdx.x;
  const int dir  = wg >> 6;
  const int slot = wg & 63;
  const int u0   = slot << 4;         // 16 units per WG

  if (wg == 0 && tid < B_)
    out[(size_t)B_*T_*2*U_ + tid] = (float)xlen[tid];

  const float* Km = dir ? kb  : kf;
  const float* Rm = dir ? rkb : rkf;
  const float* Bv = dir ? bb_ : bf_;

  const int w = tid >> 6, l = tid & 63;
  const int ntile = w >> 1, khalf = w & 1;    // 4 col-tiles x 2 khalf
  const int fr8 = (l >> 4) << 3;              // frag k-offset (elems)
  const int col = ntile*16 + (l & 15);        // col = gate*16 + unit_local

  // ---- one-time: 2-pass weight staging + frag extraction into VGPRs ----
  bf16x8 wx[8], wh[16];
  {
    unsigned short* stag = (unsigned short*)smem;
    #pragma unroll
    for (int p = 0; p < 2; ++p) {
      for (int i = tid; i < 768*NCOL; i += TPB) {
        int kl = i >> 6, c = i & 63;
        int k = p*768 + kl;
        int gc = (c >> 4)*1024 + u0 + (c & 15);     // gate*1024 + unit
        float wv = (k < D_) ? Km[(size_t)k*G_ + gc] : Rm[(size_t)(k-D_)*G_ + gc];
        stag[c*SSTR + kl] = f2bf(wv);
      }
      __syncthreads();
      const unsigned short* srow = stag + col*SSTR;
      #pragma unroll
      for (int i = 0; i < 8; ++i) {
        int kb_ = khalf*256 + i*32 + fr8;           // x frag base, < 512
        if ((kb_ >> 9) == 0 && p == 0) wx[i] = *(const bf16x8*)(srow + kb_);
      }
      #pragma unroll
      for (int i = 0; i < 16; ++i) {
        int kb_ = 512 + khalf*512 + i*32 + fr8;     // h frag base, < 1536
        if ((kb_ >= p*768) && (kb_ < (p+1)*768))
          wh[i] = *(const bf16x8*)(srow + (kb_ - p*768));
      }
      __syncthreads();
    }
  }

  float* gates = (float*)smem;          // [2 khalf][16 b][GSTR] = 8704 B
  char*  hst   = smem + HSTOFF;         // [16 b][2048 B] swizzled bf16 h payload
  float* gp    = gates + khalf*(16*GSTR);
  const int drow0 = (l >> 4) << 2;

  // epilogue state (waves 0-1: 128 lanes): b = tid>>3, units ul2, ul2+1
  const int eb = tid >> 3, eu = (tid & 7) << 1;
  float bias[8]; float cc0 = 0.f, cc1 = 0.f;
  if (tid < 128) {
    #pragma unroll
    for (int g = 0; g < 4; ++g) {
      bias[g]     = Bv[g*1024 + u0 + eu];
      bias[4 + g] = Bv[g*1024 + u0 + eu + 1];
    }
  }

  // per-lane x bases (row = l&15)
  const float* xbase = x + (size_t)(l & 15)*T_*D_ + khalf*256 + fr8;
  const unsigned short* x16b = x16 + (size_t)(l & 15)*T_*D_ + khalf*256 + fr8;

  // h A-frag LDS read base
  const char* hrow = hst + (l & 15)*2048;
  const int   swz  = ((l & 15) & 7) << 4;

  // consumer poll map: 8 x 16B chunks/thread over the 64KB tagged image
  const unsigned off0 = (unsigned)tid * 16;
  const int hb_b0 = tid >> 8;                 // b = 2*j + (tid>>8)
  const int hb_in = (tid & 255) << 3;         // payload byte offset within row

  // prologue: x-projection for t=0
  f32x4 acc = {0.f, 0.f, 0.f, 0.f};
  {
    const int tg0 = dir ? (T_ - 1) : 0;
    if (use16) {
      const unsigned short* xA = x16b + (size_t)tg0 * D_;
      #pragma unroll
      for (int i = 0; i < 8; ++i)
        acc = __builtin_amdgcn_mfma_f32_16x16x32_bf16(*(const bf16x8*)(xA + i*32), wx[i], acc, 0, 0, 0);
    } else {
      const float* xA = xbase + (size_t)tg0 * D_;
      #pragma unroll
      for (int i = 0; i < 8; ++i) {
        float4 lo = *(const float4*)(xA + i*32);
        float4 hi = *(const float4*)(xA + i*32 + 4);
        acc = __builtin_amdgcn_mfma_f32_16x16x32_bf16(cvt8(lo, hi), wx[i], acc, 0, 0, 0);
      }
    }
  }

  for (int t = 0; t < T_; ++t) {
    const int tg = dir ? (T_ - 1 - t) : t;

    if (t > 0) {
      // fused poll+load: retry until all 8B granules carry tag t
      const u32* hb = hbuf32 + (size_t)((t & 1)*2 + dir) * 16384;
      const unsigned tagv = (unsigned)t << 16;
      uint4v hv[8];
      long long guard = 0;
      for (;;) {
        #pragma unroll
        for (int j = 0; j < 8; ++j)
          asm volatile("global_load_dwordx4 %0, %1, %2 sc0 sc1"
                       : "=v"(hv[j]) : "v"(off0 + (unsigned)(j*8192)), "s"(hb));
        asm volatile("s_waitcnt vmcnt(0)" ::: "memory");
        __builtin_amdgcn_sched_barrier(0);
        unsigned bad = 0;
        #pragma unroll
        for (int j = 0; j < 8; ++j)
          bad |= (hv[j][0] ^ tagv) | (hv[j][2] ^ tagv);
        if (!(bad & 0xFFFF0000u)) break;
        __builtin_amdgcn_s_sleep(1);
        if (++guard > (1LL << 22)) break;
      }
      // strip tags, stage payload to LDS (swizzled)
      #pragma unroll
      for (int j = 0; j < 8; ++j) {
        u32 lo = __builtin_amdgcn_perm(hv[j][1], hv[j][0], 0x05040100u);
        u32 hi = __builtin_amdgcn_perm(hv[j][3], hv[j][2], 0x05040100u);
        const int b = 2*j + hb_b0;
        *(u64*)(hst + b*2048 + (hb_in ^ ((b & 7) << 4))) = ((u64)hi << 32) | lo;
      }
      __syncthreads();   // S2: h image staged

      // recurrent MFMAs from LDS; 2 accumulators break the dep chain
      f32x4 acc2 = {0.f, 0.f, 0.f, 0.f};
      #pragma unroll
      for (int i = 0; i < 16; i += 2) {
        bf16x8 a0 = *(const bf16x8*)(hrow + ((khalf*1024 + i*64     + (fr8 << 1)) ^ swz));
        bf16x8 a1 = *(const bf16x8*)(hrow + ((khalf*1024 + (i+1)*64 + (fr8 << 1)) ^ swz));
        acc  = __builtin_amdgcn_mfma_f32_16x16x32_bf16(a0, wh[i],   acc,  0, 0, 0);
        acc2 = __builtin_amdgcn_mfma_f32_16x16x32_bf16(a1, wh[i+1], acc2, 0, 0, 0);
      }
      acc[0]+=acc2[0]; acc[1]+=acc2[1]; acc[2]+=acc2[2]; acc[3]+=acc2[3];
    }

    #pragma unroll
    for (int j = 0; j < 4; ++j) gp[(drow0 + j)*GSTR + col] = acc[j];
    __syncthreads();   // S3: gates ready; h-image reads done

    // epilogue: waves 0-1 (2 units per lane); tagged self-publishing h store
    if (tid < 128) {
      const float* ga = gates + eb*GSTR + eu;
      const float* gb2 = gates + (16 + eb)*GSTR + eu;
      f32x2 ia = *(const f32x2*)(ga);      f32x2 ib = *(const f32x2*)(gb2);
      f32x2 fa = *(const f32x2*)(ga + 16); f32x2 fb = *(const f32x2*)(gb2 + 16);
      f32x2 za = *(const f32x2*)(ga + 32); f32x2 zb = *(const f32x2*)(gb2 + 32);
      f32x2 oa = *(const f32x2*)(ga + 48); f32x2 ob = *(const f32x2*)(gb2 + 48);
      float gi0 = ia.x + ib.x + bias[0], gi1 = ia.y + ib.y + bias[4];
      float gf0 = fa.x + fb.x + bias[1], gf1 = fa.y + fb.y + bias[5];
      float gz0 = za.x + zb.x + bias[2], gz1 = za.y + zb.y + bias[6];
      float go0 = oa.x + ob.x + bias[3], go1 = oa.y + ob.y + bias[7];
      cc0 = sigm(gf0)*cc0 + sigm(gi0)*tanh_(gz0);
      cc1 = sigm(gf1)*cc1 + sigm(gi1)*tanh_(gz1);
      float h0 = sigm(go0)*tanh_(cc0);
      float h1 = sigm(go1)*tanh_(cc1);
      const unsigned tagw = (unsigned)(t + 1) << 16;
      u32 w0 = (u32)f2bf(h0) | tagw;
      u32 w1 = (u32)f2bf(h1) | tagw;
      u32* hdst = hbuf32 + (size_t)(((t & 1) ^ 1)*2 + dir)*16384 + (eb << 10) + u0 + eu;
      __hip_atomic_store((u64*)hdst, ((u64)w1 << 32) | w0, __ATOMIC_RELAXED, __HIP_MEMORY_SCOPE_AGENT);
      f32x2 ho; ho.x = h0; ho.y = h1;   // out store off the critical path, cached
      *(f32x2*)(out + ((size_t)eb*T_ + tg)*(2*U_) + (dir << 10) + u0 + eu) = ho;
    }

    if (t + 1 < T_) {
      // x-projection for t+1 (overlaps h-store propagation)
      const int tg1 = dir ? (T_ - 2 - t) : (t + 1);
      f32x4 nacc = {0.f, 0.f, 0.f, 0.f};
      if (use16) {
        const unsigned short* xA = x16b + (size_t)tg1 * D_;
        #pragma unroll
        for (int i = 0; i < 8; ++i)
          nacc = __builtin_amdgcn_mfma_f32_16x16x32_bf16(*(const bf16x8*)(xA + i*32), wx[i], nacc, 0, 0, 0);
      } else {
        const float* xA = xbase + (size_t)tg1 * D_;
        #pragma unroll
        for (int i = 0; i < 8; ++i) {
          float4 lo = *(const float4*)(xA + i*32);
          float4 hi = *(const float4*)(xA + i*32 + 4);
          nacc = __builtin_amdgcn_mfma_f32_16x16x32_bf16(cvt8(lo, hi), wx[i], nacc, 0, 0, 0);
        }
      }
      acc = nacc;
    }
  }
}

extern "C" void kernel_launch(void* const* d_in, const int* in_sizes, int n_in,
                              void* d_out, int out_size, void* d_ws, size_t ws_size,
                              hipStream_t stream) {
  const float* x   = (const float*)d_in[0];
  const int*   xl  = (const int*)d_in[1];
  const float* kf  = (const float*)d_in[2];
  const float* rkf = (const float*)d_in[3];
  const float* bf_ = (const float*)d_in[4];
  const float* kb  = (const float*)d_in[5];
  const float* rkb = (const float*)d_in[6];
  const float* bb_ = (const float*)d_in[7];
  float* out = (float*)d_out;

  u32* hbuf32 = (u32*)d_ws;                                       // 4 x 64KB tagged h images
  unsigned short* x16 = (unsigned short*)((char*)d_ws + X16OFF);  // 26.2 MB bf16 x

  const size_t need = (size_t)X16OFF + (size_t)B_*T_*D_*2;
  const int use16 = (ws_size >= need) ? 1 : 0;

  (void)hipMemsetAsync(d_ws, 0, X16OFF, stream);    // zero all tags (graph-safe)
  if (use16)
    xcvt_kernel<<<6400, 256, 0, stream>>>(x, x16);

  bilstm_kernel<<<NWG, TPB, SMEM_BYTES, stream>>>(x, xl, kf, rkf, bf_, kb, rkb, bb_,
                                                  out, hbuf32, x16, use16);
}